// Round 19
// baseline (940.085 us; speedup 1.0000x reference)
//
#include <hip/hip_runtime.h>

#define NB 32
#define NT 1024
#define ND 1024
#define NH 1024
#define G3 3072          // 3*NH
#define MROWS 32768      // NB*NT
#define HROWS 16512      // h-state rows (>= max Ak + tile pad)
#define GSROWS 32896     // MROWS + 128 pad (over-read guard)
#define TAILG 256        // tail grid: 4 blocks per col-slice (cs=bid&63, rg=bid>>6)

typedef __bf16 bf16x8 __attribute__((ext_vector_type(8)));
typedef float f32x4 __attribute__((ext_vector_type(4)));
typedef unsigned short u16x8 __attribute__((ext_vector_type(8)));
typedef unsigned short u16x4 __attribute__((ext_vector_type(4)));

__device__ __forceinline__ float b2f(unsigned short u){
  union { unsigned int i; float f; } v; v.i = ((unsigned int)u) << 16; return v.f;
}
__device__ __forceinline__ unsigned short f2b(float f){
  union { float f; unsigned int i; } v; v.f = f;
  unsigned int r = (v.i + 0x7FFFu + ((v.i >> 16) & 1u)) >> 16;
  return (unsigned short)r;
}
__device__ __forceinline__ float sigm(float x){ return 1.0f / (1.0f + __expf(-x)); }
__device__ __forceinline__ float tanh_(float x){ return 2.0f / (1.0f + __expf(-2.0f * x)) - 1.0f; }

__device__ __forceinline__ void g2l16(const void* g, void* l){
  __builtin_amdgcn_global_load_lds((__attribute__((address_space(1))) void*)g,
                                   (__attribute__((address_space(3))) void*)l, 16, 0, 0);
}

// coherent (cross-XCD) fine-grained accesses (validated R11)
__device__ __forceinline__ unsigned long long ld_agent_u64(const unsigned short* p){
  return __hip_atomic_load((const unsigned long long*)p, __ATOMIC_RELAXED,
                           __HIP_MEMORY_SCOPE_AGENT);
}
__device__ __forceinline__ unsigned short ld_agent_u16(const unsigned short* p){
  return __hip_atomic_load(p, __ATOMIC_RELAXED, __HIP_MEMORY_SCOPE_AGENT);
}
__device__ __forceinline__ void st_agent_u16(unsigned short* p, unsigned short v){
  __hip_atomic_store(p, v, __ATOMIC_RELAXED, __HIP_MEMORY_SCOPE_AGENT);
}

// ---------------- K1: setup + fused segbuild (R18; R19 drops the out zero-fill) ----------
__global__ __launch_bounds__(1024) void k_setup(const float* __restrict__ wih,
    const float* __restrict__ whh, const float* __restrict__ x,
    unsigned short* __restrict__ wih_b, unsigned short* __restrict__ whh_b,
    unsigned short* __restrict__ x_b, int has_xb,
    const int* __restrict__ seg,
    int* __restrict__ ugi, int* __restrict__ uout, int* __restrict__ ulen,
    int* __restrict__ nseg_b,
    int* __restrict__ sgi, int* __restrict__ sout, int* __restrict__ slen,
    int* __restrict__ cnt_ge, int* __restrict__ base_g,
    unsigned int* __restrict__ perm, unsigned int* __restrict__ bar,
    float* __restrict__ counts_out){
  int tid = threadIdx.x;
  if (blockIdx.x == gridDim.x - 1){
    // ---- segbuild (unchanged body, validated R16) ----
    __shared__ int hist[1025];
    __shared__ int sufx[1024];
    __shared__ int pref[1024];
    __shared__ int offs[1025];
    int wave = tid >> 6, lane = tid & 63;
    if (tid == 0) *bar = 0u;    // reset persistent-tail barrier (replay-safe)

    for (int b = wave; b < NB; b += 16){
      int prev = -1;
      int zc = 0;
      for (int c = 0; c < 16; ++c){
        int t = c * 64 + lane;
        int v = seg[b * NT + t];
        unsigned long long mask = __ballot(v == 0);
        unsigned long long below = mask & ((1ULL << lane) - 1ULL);
        if (v == 0){
          int pz = below ? (c * 64 + (63 - __clzll((long long)below))) : prev;
          int eidx = zc + __popcll(below);
          int slot = b * NT + eidx;
          ugi[slot]  = b * NT + (pz + 1);
          uout[slot] = b * NT + eidx;
          ulen[slot] = t - pz;
        }
        if (mask) prev = c * 64 + (63 - __clzll((long long)mask));
        zc += __popcll(mask);
      }
      if (lane == 0){ nseg_b[b] = zc; counts_out[b] = (float)zc; }
    }
    __syncthreads();
    for (int i = tid; i <= 1024; i += 1024) hist[i] = 0;
    __syncthreads();
    for (int s = tid; s < NB * NT; s += 1024){
      int b = s >> 10, j = s & 1023;
      if (j < nseg_b[b]) atomicAdd(&hist[ulen[s]], 1);
    }
    __syncthreads();
    if (tid < 1024) sufx[tid] = hist[tid + 1];
    __syncthreads();
    for (int off = 1; off < 1024; off <<= 1){
      int v = (tid + off < 1024) ? sufx[tid + off] : 0;
      __syncthreads();
      sufx[tid] += v;
      __syncthreads();
    }
    cnt_ge[tid + 1] = sufx[tid];
    if (tid == 0){ cnt_ge[0] = sufx[0]; cnt_ge[1025] = 0; }
    offs[tid] = sufx[tid];
    if (tid == 0) offs[1024] = 0;
    pref[tid] = sufx[tid];
    __syncthreads();
    for (int off = 1; off < 1024; off <<= 1){
      int v = (tid >= off) ? pref[tid - off] : 0;
      __syncthreads();
      pref[tid] += v;
      __syncthreads();
    }
    base_g[tid + 1] = pref[tid];
    if (tid == 0){ base_g[0] = 0; base_g[1025] = pref[1023]; }
    __syncthreads();
    for (int s = tid; s < NB * NT; s += 1024){
      int b = s >> 10, j = s & 1023;
      if (j < nseg_b[b]){
        int len = ulen[s];
        int p = atomicAdd(&offs[len], 1);
        sgi[p] = ugi[s]; sout[p] = uout[s]; slen[p] = len;
      }
    }
    for (int m = tid; m < MROWS; m += 1024) perm[m] = 0xFFFFFFFFu;
    __syncthreads();
    int nseg = cnt_ge[1];
    for (int p = tid; p < nseg; p += 1024){
      int src = sgi[p];
      int len = slen[p];
      perm[src] = (unsigned int)p;
      for (int kk = 1; kk < len; ++kk)
        perm[src + kk] = (unsigned int)(pref[kk - 1] + p);
    }
    return;
  }
  // ---- setup (conversion) blocks ----
  int i0 = blockIdx.x * 1024 + tid;
  int stride = (gridDim.x - 1) * 1024;
  int nw4 = (G3 * ND) / 4;
  for (int j = i0; j < nw4; j += stride){
    f32x4 a = ((const f32x4*)wih)[j];
    f32x4 b = ((const f32x4*)whh)[j];
    u16x4 ua = {f2b(a[0]), f2b(a[1]), f2b(a[2]), f2b(a[3])};
    u16x4 ub = {f2b(b[0]), f2b(b[1]), f2b(b[2]), f2b(b[3])};
    ((u16x4*)wih_b)[j] = ua;
    ((u16x4*)whh_b)[j] = ub;
  }
  if (has_xb){
    int nx4 = (MROWS * ND) / 4;
    for (int j = i0; j < nx4; j += stride){
      f32x4 a = ((const f32x4*)x)[j];
      u16x4 u = {f2b(a[0]), f2b(a[1]), f2b(a[2]), f2b(a[3])};
      ((u16x4*)x_b)[j] = u;
    }
  }
}

// ---------------- K3: Gi = x @ W_ih^T + b_ih -> bf16, permuted rows ----------------
// R16-validated: epilogue transposes each wave's 64x64 quadrant through the
// already-allocated Alds/Blds (zero extra LDS) -> full 128B-line plain stores to gs.
__global__ __launch_bounds__(256, 2) void k_gi_gemm(const float* __restrict__ x,
    const unsigned short* __restrict__ x_b, const unsigned short* __restrict__ wih_b,
    const float* __restrict__ b_ih, const unsigned int* __restrict__ perm,
    unsigned short* __restrict__ gs, int use_xb){
  __shared__ unsigned short Alds[128 * 64];
  __shared__ unsigned short Blds[128 * 64];
  int tid = threadIdx.x;
  int w = tid >> 6, lane = tid & 63;
  int mtile = blockIdx.x / 24, ntile = blockIdx.x % 24;
  int m0 = mtile * 128, n0 = ntile * 128;
  int mh = (w >> 1) * 64, nh = (w & 1) * 64;
  int lrow = lane >> 3;
  int lcol = 8 * ((lane & 7) ^ lrow);
  f32x4 acc[4][4];
#pragma unroll
  for (int i = 0; i < 4; ++i)
#pragma unroll
    for (int j = 0; j < 4; ++j) acc[i][j] = (f32x4){0.f, 0.f, 0.f, 0.f};

  for (int kc = 0; kc < 16; ++kc){
    __syncthreads();
    if (use_xb){
#pragma unroll
      for (int p = 0; p < 4; ++p){
        int s = w * 4 + p;
        g2l16(x_b + (size_t)(m0 + s * 8 + lrow) * ND + kc * 64 + lcol, &Alds[s * 512]);
      }
    } else {
#pragma unroll
      for (int p = 0; p < 4; ++p){
        int e = (p * 256 + tid) * 8;
        int r = e >> 6, c = e & 63;
        const float* src = x + (size_t)(m0 + r) * ND + kc * 64 + c;
        f32x4 f0 = *(const f32x4*)src;
        f32x4 f1 = *(const f32x4*)(src + 4);
        u16x8 u;
        u[0]=f2b(f0[0]); u[1]=f2b(f0[1]); u[2]=f2b(f0[2]); u[3]=f2b(f0[3]);
        u[4]=f2b(f1[0]); u[5]=f2b(f1[1]); u[6]=f2b(f1[2]); u[7]=f2b(f1[3]);
        *(u16x8*)&Alds[r * 64 + (c ^ ((r & 7) << 3))] = u;
      }
    }
#pragma unroll
    for (int p = 0; p < 4; ++p){
      int s = w * 4 + p;
      g2l16(wih_b + (size_t)(n0 + s * 8 + lrow) * ND + kc * 64 + lcol, &Blds[s * 512]);
    }
    __syncthreads();
#pragma unroll
    for (int ks = 0; ks < 2; ++ks){
      int co = ks * 32 + (lane >> 4) * 8;
      int cx = co ^ ((lane & 7) << 3);
      bf16x8 a[4], bb[4];
#pragma unroll
      for (int mi = 0; mi < 4; ++mi)
        a[mi] = *(const bf16x8*)&Alds[(mh + mi * 16 + (lane & 15)) * 64 + cx];
#pragma unroll
      for (int ni = 0; ni < 4; ++ni)
        bb[ni] = *(const bf16x8*)&Blds[(nh + ni * 16 + (lane & 15)) * 64 + cx];
#pragma unroll
      for (int mi = 0; mi < 4; ++mi)
#pragma unroll
        for (int ni = 0; ni < 4; ++ni)
          acc[mi][ni] = __builtin_amdgcn_mfma_f32_16x16x32_bf16(a[mi], bb[ni], acc[mi][ni], 0, 0, 0);
    }
  }

  // ---- epilogue: retire last MFMA reads, then reuse Alds/Blds as transpose scratch ----
  __syncthreads();
  unsigned short* E = (w & 2) ? &Blds[(w & 1) * 4096] : &Alds[(w & 1) * 4096];
#pragma unroll
  for (int mi = 0; mi < 4; ++mi){
#pragma unroll
    for (int rr = 0; rr < 4; ++rr){
      int row_l = mi * 16 + (lane >> 4) * 4 + rr;
#pragma unroll
      for (int ni = 0; ni < 4; ++ni){
        int col_l = ni * 16 + (lane & 15);
        E[row_l * 64 + (col_l ^ ((row_l & 7) << 3))] =
            f2b(acc[mi][ni][rr] + b_ih[n0 + nh + col_l]);
      }
    }
  }
  int r8 = lane >> 3, j8 = lane & 7;
#pragma unroll
  for (int sg = 0; sg < 8; ++sg){
    int row_l = sg * 8 + r8;
    unsigned int prow = perm[m0 + mh + row_l];
    if (prow != 0xFFFFFFFFu){
      u16x8 v = *(const u16x8*)&E[row_l * 64 + ((j8 * 8) ^ ((row_l & 7) << 3))];
      *(u16x8*)(gs + (size_t)prow * G3 + n0 + nh + j8 * 8) = v;
    }
  }
}

// ---------------- step 0: fused targeted zero + elementwise over Gsort region 0 ----------
// R19: zero only non-emitted out rows (t >= nsegb[b]); emitted rows are written by the
// pipeline. Replaces the 128MB blind zero-fill that was in setup.
__global__ __launch_bounds__(256) void k_step0(const float* __restrict__ b_hh,
    const unsigned short* __restrict__ gs,
    const int* __restrict__ sout, const int* __restrict__ cnt_ge,
    const int* __restrict__ nseg_b,
    unsigned short* __restrict__ hbuf, float* __restrict__ out){
  int nseg = cnt_ge[1];
  int c2 = cnt_ge[2];
  // phase A: targeted zero of non-emitted rows
  int ztotal = MROWS * 128;
  f32x4 z = {0.f, 0.f, 0.f, 0.f};
  for (int idx = blockIdx.x * 256 + threadIdx.x; idx < ztotal; idx += gridDim.x * 256){
    int r = idx >> 7;
    if ((r & 1023) >= nseg_b[r >> 10]){
      int c0 = (idx & 127) * 8;
      float* orow = out + (size_t)r * NH + c0;
      __builtin_nontemporal_store(z, (f32x4*)orow);
      __builtin_nontemporal_store(z, (f32x4*)(orow + 4));
    }
  }
  // phase B: step-0 gates
  int total = nseg * 128;
  for (int idx = blockIdx.x * 256 + threadIdx.x; idx < total; idx += gridDim.x * 256){
    int i = idx >> 7;
    int c0 = (idx & 127) * 8;
    bool emit = (i >= c2);   // len == 1
    const unsigned short* g = gs + (size_t)i * G3;
    u16x8 vr = __builtin_nontemporal_load((const u16x8*)(g + c0));
    u16x8 vz = __builtin_nontemporal_load((const u16x8*)(g + NH + c0));
    u16x8 vn = __builtin_nontemporal_load((const u16x8*)(g + 2 * NH + c0));
    float hn[8];
#pragma unroll
    for (int j = 0; j < 8; ++j){
      int c = c0 + j;
      float r = sigm(b2f(vr[j]) + b_hh[c]);
      float z2 = sigm(b2f(vz[j]) + b_hh[NH + c]);
      float n = tanh_(b2f(vn[j]) + r * b_hh[2 * NH + c]);
      hn[j] = (1.0f - z2) * n;
    }
    if (emit){
      float* orow = out + (size_t)sout[i] * NH + c0;
      f32x4 v0 = {hn[0], hn[1], hn[2], hn[3]};
      f32x4 v1 = {hn[4], hn[5], hn[6], hn[7]};
      __builtin_nontemporal_store(v0, (f32x4*)orow);
      __builtin_nontemporal_store(v1, (f32x4*)(orow + 4));
    } else {
      u16x8 u;
#pragma unroll
      for (int j = 0; j < 8; ++j) u[j] = f2b(hn[j]);
      *(u16x8*)(hbuf + (size_t)HROWS * NH + (size_t)i * NH + c0) = u;
    }
  }
}

// ---------------- step-tile (k=1..2 big steps): M64 x (3x64), BK=128, 8 phases ----------------
__device__ __forceinline__ void step_tile(int m0, int nc0, int Ak, int c2, int gbase,
    const unsigned short* __restrict__ whh_b, const float* __restrict__ b_hh,
    const unsigned short* __restrict__ gs, const int* __restrict__ sout,
    const unsigned short* __restrict__ hread, unsigned short* __restrict__ hwrite,
    float* __restrict__ out,
    unsigned short (*Alds)[64 * 128], unsigned short (*Blds)[192 * 128]){
  int tid = threadIdx.x;
  int w = tid >> 6, lane = tid & 63;
  int l15 = lane & 15, l4 = lane >> 4;

#define STAGE2(buf, kc) do {                                                        \
    _Pragma("unroll")                                                               \
    for (int p = 0; p < 4; ++p){                                                    \
      int s = w * 4 + p;                                                            \
      int ar = s * 4 + l4;                                                          \
      int sc = (l15 * 8) ^ ((ar & 7) << 3);                                         \
      g2l16(hread + (size_t)(m0 + ar) * NH + (kc) * 128 + sc, &Alds[buf][s * 512]); \
    }                                                                               \
    _Pragma("unroll")                                                               \
    for (int p = 0; p < 12; ++p){                                                   \
      int s = w * 12 + p;                                                           \
      int br = s * 4 + l4;                                                          \
      int wrow = (br >> 6) * NH + nc0 + (br & 63);                                  \
      int sc = (l15 * 8) ^ ((br & 7) << 3);                                         \
      g2l16(whh_b + (size_t)wrow * NH + (kc) * 128 + sc, &Blds[buf][s * 512]);      \
    }                                                                               \
  } while (0)

  STAGE2(0, 0);

  // epilogue-operand prefetch (hidden under the K-loop); gs is stream-once -> nt loads
  int c_lane = nc0 + w * 16 + l15;
  float bh_r = b_hh[c_lane], bh_z = b_hh[NH + c_lane], bh_n = b_hh[2 * NH + c_lane];
  unsigned short gr_[4][4], gz_[4][4], gn_[4][4], hv_[4][4];
  int so_[4][4];
#pragma unroll
  for (int a = 0; a < 4; ++a){
#pragma unroll
    for (int rr = 0; rr < 4; ++rr){
      int i = m0 + a * 16 + l4 * 4 + rr;
      const unsigned short* g = gs + (size_t)(gbase + i) * G3 + c_lane;
      gr_[a][rr] = __builtin_nontemporal_load(g);
      gz_[a][rr] = __builtin_nontemporal_load(g + NH);
      gn_[a][rr] = __builtin_nontemporal_load(g + 2 * NH);
      hv_[a][rr] = hread[(size_t)i * NH + c_lane];
      so_[a][rr] = sout[i < MROWS ? i : 0];
    }
  }

  f32x4 acc[4][3];
#pragma unroll
  for (int a = 0; a < 4; ++a)
#pragma unroll
    for (int b = 0; b < 3; ++b) acc[a][b] = (f32x4){0.f, 0.f, 0.f, 0.f};

  __syncthreads();
  int cur = 0;
  for (int kc = 0; kc < 8; ++kc){
    if (kc < 7) STAGE2(cur ^ 1, kc + 1);
#pragma unroll
    for (int ks = 0; ks < 4; ++ks){
      int co = ks * 32 + l4 * 8;
      bf16x8 av[4], bv[3];
#pragma unroll
      for (int a = 0; a < 4; ++a){
        int r = a * 16 + l15;
        av[a] = *(const bf16x8*)&Alds[cur][r * 128 + (co ^ ((r & 7) << 3))];
      }
#pragma unroll
      for (int b = 0; b < 3; ++b){
        int br = 64 * b + w * 16 + l15;
        bv[b] = *(const bf16x8*)&Blds[cur][br * 128 + (co ^ ((br & 7) << 3))];
      }
#pragma unroll
      for (int a = 0; a < 4; ++a)
#pragma unroll
        for (int b = 0; b < 3; ++b)
          acc[a][b] = __builtin_amdgcn_mfma_f32_16x16x32_bf16(av[a], bv[b], acc[a][b], 0, 0, 0);
    }
    __syncthreads();
    cur ^= 1;
  }
#undef STAGE2

  // fused gate epilogue: one column per lane, 16 rows
#pragma unroll
  for (int a = 0; a < 4; ++a){
#pragma unroll
    for (int rr = 0; rr < 4; ++rr){
      int i = m0 + a * 16 + l4 * 4 + rr;
      if (i >= Ak) continue;
      bool emit = (i >= c2);    // len == k+1
      float ghr = acc[a][0][rr] + bh_r;
      float ghz = acc[a][1][rr] + bh_z;
      float ghn = acc[a][2][rr] + bh_n;
      float h = b2f(hv_[a][rr]);
      float r = sigm(b2f(gr_[a][rr]) + ghr);
      float z = sigm(b2f(gz_[a][rr]) + ghz);
      float n = tanh_(b2f(gn_[a][rr]) + r * ghn);
      float hn = (1.0f - z) * n + z * h;
      if (emit) __builtin_nontemporal_store(hn, &out[(size_t)so_[a][rr] * NH + c_lane]);
      else      hwrite[(size_t)i * NH + c_lane] = f2b(hn);
    }
  }
}

// ---------------- per-step regular kernel (k = 1..2) ----------------
__global__ __launch_bounds__(256, 1) void k_step(int k,
    const unsigned short* __restrict__ whh_b, const float* __restrict__ b_hh,
    const unsigned short* __restrict__ gs, const int* __restrict__ base_g,
    const int* __restrict__ sout, const int* __restrict__ cnt_ge,
    unsigned short* __restrict__ hbuf, float* __restrict__ out){
  __shared__ unsigned short Alds[2][64 * 128];    // 32 KB
  __shared__ unsigned short Blds[2][192 * 128];   // 96 KB
  int Ak = cnt_ge[k + 1];
  if (Ak <= 0) return;
  int c2 = cnt_ge[k + 2];
  int gbase = base_g[k];
  int Mt = (Ak + 63) >> 6;
  int tiles = Mt * 16;
  const unsigned short* hread = hbuf + (size_t)(k & 1) * HROWS * NH;
  unsigned short* hwrite      = hbuf + (size_t)((k + 1) & 1) * HROWS * NH;
  for (int t = blockIdx.x; t < tiles; t += gridDim.x){
    int cs = t & 15, mt = t >> 4;   // gridDim%16==0 -> cs stationary per block
    step_tile(mt * 64, cs * 64, Ak, c2, gbase, whh_b, b_hh, gs, sout,
              hread, hwrite, out, Alds, Blds);
  }
}

// ---------------- persistent tail (k >= 3): W in LDS, 4 blocks/col-slice ----------------
// R17-validated geometry (TAILG=256: cs=bid&63, rg=bid>>6); R19 moves k=3 in as well.
__global__ __launch_bounds__(256, 1) void k_tail(
    const unsigned short* __restrict__ whh_b, const float* __restrict__ b_hh,
    const unsigned short* __restrict__ gs, const int* __restrict__ base_g,
    const int* __restrict__ sout, const int* __restrict__ cnt_ge,
    unsigned short* __restrict__ hbuf, float* __restrict__ out,
    unsigned int* __restrict__ bar){
  __shared__ unsigned short Wlds[48 * 1024];    // 96 KB
  int tid = threadIdx.x;
  int w = tid >> 6, lane = tid & 63;
  int l15 = lane & 15, l4 = lane >> 4;
  int cs = blockIdx.x & 63;                     // col-slice
  int rg = blockIdx.x >> 6;                     // row-group 0..3

  // one-time W preload: LDS[j][c'] = W[grow(j)][c' ^ ((j&7)<<3)], j = gate*16 + col
#pragma unroll
  for (int p = 0; p < 24; ++p){
    int s = w * 24 + p;                         // 0..95
    int r = s >> 1, h = s & 1;
    int grow = (r >> 4) * NH + cs * 16 + (r & 15);
    int cp = h * 512 + lane * 8;
    g2l16(whh_b + (size_t)grow * NH + (cp ^ ((r & 7) << 3)),
          &Wlds[r * 1024 + h * 512 + lane * 8]);
  }
  __syncthreads();                              // drains vmcnt: W resident

  int c_lane = cs * 16 + l15;
  float bh_r = b_hh[c_lane], bh_z = b_hh[NH + c_lane], bh_n = b_hh[2 * NH + c_lane];

  unsigned int phase = 0;
  for (int k = 3; k <= 1023; ++k){
    int Ak = cnt_ge[k + 1];                     // uniform across blocks (read-only)
    if (Ak <= 0) break;
    int c2 = cnt_ge[k + 2];
    int gbase = base_g[k];
    int Mt16 = (Ak + 15) >> 4;
    const unsigned short* hread = hbuf + (size_t)(k & 1) * HROWS * NH;
    unsigned short* hwrite      = hbuf + (size_t)((k + 1) & 1) * HROWS * NH;

    for (int mt = rg * 4 + w; mt < Mt16; mt += 16){
      int m0 = mt * 16;
      unsigned short gr_[4], gz_[4], gn_[4], hv_[4];
      int so_[4];
#pragma unroll
      for (int rr = 0; rr < 4; ++rr){
        int i = m0 + l4 * 4 + rr;
        const unsigned short* g = gs + (size_t)(gbase + i) * G3 + c_lane;
        gr_[rr] = __builtin_nontemporal_load(g);
        gz_[rr] = __builtin_nontemporal_load(g + NH);
        gn_[rr] = __builtin_nontemporal_load(g + 2 * NH);
        hv_[rr] = ld_agent_u16(hread + (size_t)i * NH + c_lane);
        so_[rr] = sout[i < MROWS ? i : 0];
      }

      const unsigned short* arow = hread + (size_t)(m0 + l15) * NH + l4 * 8;
      f32x4 acc0 = {0.f, 0.f, 0.f, 0.f}, acc1 = acc0, acc2 = acc0;
#pragma unroll 8
      for (int ks = 0; ks < 32; ++ks){
        int co = ks * 32 + l4 * 8;
        union { bf16x8 v; unsigned long long q[2]; } a;
        a.q[0] = ld_agent_u64(arow + ks * 32);
        a.q[1] = ld_agent_u64(arow + ks * 32 + 4);
        int cx = co ^ ((l15 & 7) << 3);
        bf16x8 b0 = *(const bf16x8*)&Wlds[(0 * 16 + l15) * 1024 + cx];
        bf16x8 b1 = *(const bf16x8*)&Wlds[(1 * 16 + l15) * 1024 + cx];
        bf16x8 b2 = *(const bf16x8*)&Wlds[(2 * 16 + l15) * 1024 + cx];
        acc0 = __builtin_amdgcn_mfma_f32_16x16x32_bf16(a.v, b0, acc0, 0, 0, 0);
        acc1 = __builtin_amdgcn_mfma_f32_16x16x32_bf16(a.v, b1, acc1, 0, 0, 0);
        acc2 = __builtin_amdgcn_mfma_f32_16x16x32_bf16(a.v, b2, acc2, 0, 0, 0);
      }

#pragma unroll
      for (int rr = 0; rr < 4; ++rr){
        int i = m0 + l4 * 4 + rr;
        if (i >= Ak) continue;
        bool emit = (i >= c2);                  // len == k+1
        float h = b2f(hv_[rr]);
        float r = sigm(b2f(gr_[rr]) + acc0[rr] + bh_r);
        float z = sigm(b2f(gz_[rr]) + acc1[rr] + bh_z);
        float n = tanh_(b2f(gn_[rr]) + r * (acc2[rr] + bh_n));
        float hn = (1.0f - z) * n + z * h;
        if (emit) __builtin_nontemporal_store(hn, &out[(size_t)so_[rr] * NH + c_lane]);
        else      st_agent_u16(hwrite + (size_t)i * NH + c_lane, f2b(hn));
      }
    }

    // fence-free device barrier (validated R11)
    ++phase;
    __syncthreads();
    if (threadIdx.x == 0){
      atomicAdd(bar, 1u);
      unsigned int goal = phase * (unsigned int)TAILG;
      while (__hip_atomic_load(bar, __ATOMIC_RELAXED, __HIP_MEMORY_SCOPE_AGENT) < goal)
        __builtin_amdgcn_s_sleep(2);
    }
    __syncthreads();
  }
}

extern "C" void kernel_launch(void* const* d_in, const int* in_sizes, int n_in,
                              void* d_out, int out_size, void* d_ws, size_t ws_size,
                              hipStream_t stream){
  (void)in_sizes; (void)n_in; (void)out_size;
  const float* x   = (const float*)d_in[0];
  const float* wih = (const float*)d_in[1];
  const float* whh = (const float*)d_in[2];
  const float* bih = (const float*)d_in[3];
  const float* bhh = (const float*)d_in[4];
  const int*   seg = (const int*)d_in[5];
  float* outp = (float*)d_out;

  char* ws = (char*)d_ws;
  size_t o_wih = 0;                                        // 6 MB
  size_t o_whh = 6291456;                                  // 6 MB
  size_t o_gs  = 12582912;                                 // Gsort bf16 ~193 MB
  size_t o_desc = o_gs + (size_t)GSROWS * G3 * 2;          // 2 MB
  size_t o_h    = o_desc + (2u << 20);                     // hbuf: 64.5 MB
  size_t o_xb   = o_h + (size_t)2 * HROWS * NH * 2;        // x_b: 64 MB
  size_t need_xb = o_xb + (size_t)MROWS * ND * 2;
  int has_xb = (ws_size >= need_xb) ? 1 : 0;

  unsigned short* wih_b = (unsigned short*)(ws + o_wih);
  unsigned short* whh_b = (unsigned short*)(ws + o_whh);
  unsigned short* gsort = (unsigned short*)(ws + o_gs);
  int* ugi  = (int*)(ws + o_desc);
  int* uout = ugi + 32768;
  int* ulen = uout + 32768;
  int* sgi  = ulen + 32768;
  int* sout = sgi + 32768;
  int* slen = sout + 32768;
  int* nsegb = slen + 32768;
  int* cntge = nsegb + 64;
  int* baseg = cntge + 1056;
  unsigned int* perm = (unsigned int*)(baseg + 1056);
  unsigned int* bar  = perm + MROWS;
  unsigned short* hbuf = (unsigned short*)(ws + o_h);
  unsigned short* x_b  = (unsigned short*)(ws + o_xb);

  float* counts_out = outp + (size_t)NB * NT * NH;

  k_setup<<<dim3(513), dim3(1024), 0, stream>>>(wih, whh, x, wih_b, whh_b, x_b, has_xb,
                                                seg, ugi, uout, ulen, nsegb,
                                                sgi, sout, slen, cntge, baseg,
                                                perm, bar, counts_out);

  k_gi_gemm<<<dim3(256 * 24), dim3(256), 0, stream>>>(x, x_b, wih_b, bih, perm, gsort, has_xb);

  k_step0<<<dim3(1024), dim3(256), 0, stream>>>(bhh, gsort, sout, cntge, nsegb, hbuf, outp);

  for (int k = 1; k <= 2; ++k){
    k_step<<<dim3(256), dim3(256), 0, stream>>>(k, whh_b, bhh, gsort, baseg,
                                                sout, cntge, hbuf, outp);
  }

  k_tail<<<dim3(TAILG), dim3(256), 0, stream>>>(whh_b, bhh, gsort, baseg,
                                                sout, cntge, hbuf, outp, bar);
}

// Round 20
// 906.087 us; speedup vs baseline: 1.0375x; 1.0375x over previous
//
#include <hip/hip_runtime.h>

#define NB 32
#define NT 1024
#define ND 1024
#define NH 1024
#define G3 3072          // 3*NH
#define MROWS 32768      // NB*NT
#define HROWS 16512      // h-state rows (>= max Ak + tile pad)
#define GSROWS 32896     // MROWS + 128 pad (over-read guard)
#define TAILG 256        // tail grid: 4 blocks per col-slice (cs=bid&63, rg=bid>>6)

typedef __bf16 bf16x8 __attribute__((ext_vector_type(8)));
typedef float f32x4 __attribute__((ext_vector_type(4)));
typedef unsigned short u16x8 __attribute__((ext_vector_type(8)));
typedef unsigned short u16x4 __attribute__((ext_vector_type(4)));

__device__ __forceinline__ float b2f(unsigned short u){
  union { unsigned int i; float f; } v; v.i = ((unsigned int)u) << 16; return v.f;
}
__device__ __forceinline__ unsigned short f2b(float f){
  union { float f; unsigned int i; } v; v.f = f;
  unsigned int r = (v.i + 0x7FFFu + ((v.i >> 16) & 1u)) >> 16;
  return (unsigned short)r;
}
__device__ __forceinline__ float sigm(float x){ return 1.0f / (1.0f + __expf(-x)); }
__device__ __forceinline__ float tanh_(float x){ return 2.0f / (1.0f + __expf(-2.0f * x)) - 1.0f; }

__device__ __forceinline__ void g2l16(const void* g, void* l){
  __builtin_amdgcn_global_load_lds((__attribute__((address_space(1))) void*)g,
                                   (__attribute__((address_space(3))) void*)l, 16, 0, 0);
}

// coherent (cross-XCD) fine-grained accesses (validated R11)
__device__ __forceinline__ unsigned long long ld_agent_u64(const unsigned short* p){
  return __hip_atomic_load((const unsigned long long*)p, __ATOMIC_RELAXED,
                           __HIP_MEMORY_SCOPE_AGENT);
}
__device__ __forceinline__ unsigned short ld_agent_u16(const unsigned short* p){
  return __hip_atomic_load(p, __ATOMIC_RELAXED, __HIP_MEMORY_SCOPE_AGENT);
}
__device__ __forceinline__ void st_agent_u16(unsigned short* p, unsigned short v){
  __hip_atomic_store(p, v, __ATOMIC_RELAXED, __HIP_MEMORY_SCOPE_AGENT);
}

// ---------------- K1: setup + fused segbuild (R18 configuration, 907us best) ----------------
__global__ __launch_bounds__(1024) void k_setup(const float* __restrict__ wih,
    const float* __restrict__ whh, const float* __restrict__ x,
    unsigned short* __restrict__ wih_b, unsigned short* __restrict__ whh_b,
    unsigned short* __restrict__ x_b, int has_xb, f32x4* __restrict__ outv, int out_n4,
    const int* __restrict__ seg,
    int* __restrict__ ugi, int* __restrict__ uout, int* __restrict__ ulen,
    int* __restrict__ nseg_b,
    int* __restrict__ sgi, int* __restrict__ sout, int* __restrict__ slen,
    int* __restrict__ cnt_ge, int* __restrict__ base_g,
    unsigned int* __restrict__ perm, unsigned int* __restrict__ bar,
    float* __restrict__ counts_out){
  int tid = threadIdx.x;
  if (blockIdx.x == gridDim.x - 1){
    // ---- segbuild (unchanged body, validated R16) ----
    __shared__ int hist[1025];
    __shared__ int sufx[1024];
    __shared__ int pref[1024];
    __shared__ int offs[1025];
    int wave = tid >> 6, lane = tid & 63;
    if (tid == 0) *bar = 0u;    // reset persistent-tail barrier (replay-safe)

    for (int b = wave; b < NB; b += 16){
      int prev = -1;
      int zc = 0;
      for (int c = 0; c < 16; ++c){
        int t = c * 64 + lane;
        int v = seg[b * NT + t];
        unsigned long long mask = __ballot(v == 0);
        unsigned long long below = mask & ((1ULL << lane) - 1ULL);
        if (v == 0){
          int pz = below ? (c * 64 + (63 - __clzll((long long)below))) : prev;
          int eidx = zc + __popcll(below);
          int slot = b * NT + eidx;
          ugi[slot]  = b * NT + (pz + 1);
          uout[slot] = b * NT + eidx;
          ulen[slot] = t - pz;
        }
        if (mask) prev = c * 64 + (63 - __clzll((long long)mask));
        zc += __popcll(mask);
      }
      if (lane == 0){ nseg_b[b] = zc; counts_out[b] = (float)zc; }
    }
    __syncthreads();
    for (int i = tid; i <= 1024; i += 1024) hist[i] = 0;
    __syncthreads();
    for (int s = tid; s < NB * NT; s += 1024){
      int b = s >> 10, j = s & 1023;
      if (j < nseg_b[b]) atomicAdd(&hist[ulen[s]], 1);
    }
    __syncthreads();
    if (tid < 1024) sufx[tid] = hist[tid + 1];
    __syncthreads();
    for (int off = 1; off < 1024; off <<= 1){
      int v = (tid + off < 1024) ? sufx[tid + off] : 0;
      __syncthreads();
      sufx[tid] += v;
      __syncthreads();
    }
    cnt_ge[tid + 1] = sufx[tid];
    if (tid == 0){ cnt_ge[0] = sufx[0]; cnt_ge[1025] = 0; }
    offs[tid] = sufx[tid];
    if (tid == 0) offs[1024] = 0;
    pref[tid] = sufx[tid];
    __syncthreads();
    for (int off = 1; off < 1024; off <<= 1){
      int v = (tid >= off) ? pref[tid - off] : 0;
      __syncthreads();
      pref[tid] += v;
      __syncthreads();
    }
    base_g[tid + 1] = pref[tid];
    if (tid == 0){ base_g[0] = 0; base_g[1025] = pref[1023]; }
    __syncthreads();
    for (int s = tid; s < NB * NT; s += 1024){
      int b = s >> 10, j = s & 1023;
      if (j < nseg_b[b]){
        int len = ulen[s];
        int p = atomicAdd(&offs[len], 1);
        sgi[p] = ugi[s]; sout[p] = uout[s]; slen[p] = len;
      }
    }
    for (int m = tid; m < MROWS; m += 1024) perm[m] = 0xFFFFFFFFu;
    __syncthreads();
    int nseg = cnt_ge[1];
    for (int p = tid; p < nseg; p += 1024){
      int src = sgi[p];
      int len = slen[p];
      perm[src] = (unsigned int)p;
      for (int kk = 1; kk < len; ++kk)
        perm[src + kk] = (unsigned int)(pref[kk - 1] + p);
    }
    return;
  }
  // ---- setup (conversion + zero) blocks ----
  int i0 = blockIdx.x * 1024 + tid;
  int stride = (gridDim.x - 1) * 1024;
  f32x4 z = {0.f, 0.f, 0.f, 0.f};
  for (int j = i0; j < out_n4; j += stride) __builtin_nontemporal_store(z, &outv[j]);
  int nw4 = (G3 * ND) / 4;
  for (int j = i0; j < nw4; j += stride){
    f32x4 a = ((const f32x4*)wih)[j];
    f32x4 b = ((const f32x4*)whh)[j];
    u16x4 ua = {f2b(a[0]), f2b(a[1]), f2b(a[2]), f2b(a[3])};
    u16x4 ub = {f2b(b[0]), f2b(b[1]), f2b(b[2]), f2b(b[3])};
    ((u16x4*)wih_b)[j] = ua;
    ((u16x4*)whh_b)[j] = ub;
  }
  if (has_xb){
    int nx4 = (MROWS * ND) / 4;
    for (int j = i0; j < nx4; j += stride){
      f32x4 a = ((const f32x4*)x)[j];
      u16x4 u = {f2b(a[0]), f2b(a[1]), f2b(a[2]), f2b(a[3])};
      ((u16x4*)x_b)[j] = u;
    }
  }
}

// ---------------- K3: Gi = x @ W_ih^T + b_ih -> bf16, permuted rows ----------------
// R16-validated: epilogue transposes each wave's 64x64 quadrant through the
// already-allocated Alds/Blds (zero extra LDS) -> full 128B-line plain stores to gs.
__global__ __launch_bounds__(256, 2) void k_gi_gemm(const float* __restrict__ x,
    const unsigned short* __restrict__ x_b, const unsigned short* __restrict__ wih_b,
    const float* __restrict__ b_ih, const unsigned int* __restrict__ perm,
    unsigned short* __restrict__ gs, int use_xb){
  __shared__ unsigned short Alds[128 * 64];
  __shared__ unsigned short Blds[128 * 64];
  int tid = threadIdx.x;
  int w = tid >> 6, lane = tid & 63;
  int mtile = blockIdx.x / 24, ntile = blockIdx.x % 24;
  int m0 = mtile * 128, n0 = ntile * 128;
  int mh = (w >> 1) * 64, nh = (w & 1) * 64;
  int lrow = lane >> 3;
  int lcol = 8 * ((lane & 7) ^ lrow);
  f32x4 acc[4][4];
#pragma unroll
  for (int i = 0; i < 4; ++i)
#pragma unroll
    for (int j = 0; j < 4; ++j) acc[i][j] = (f32x4){0.f, 0.f, 0.f, 0.f};

  for (int kc = 0; kc < 16; ++kc){
    __syncthreads();
    if (use_xb){
#pragma unroll
      for (int p = 0; p < 4; ++p){
        int s = w * 4 + p;
        g2l16(x_b + (size_t)(m0 + s * 8 + lrow) * ND + kc * 64 + lcol, &Alds[s * 512]);
      }
    } else {
#pragma unroll
      for (int p = 0; p < 4; ++p){
        int e = (p * 256 + tid) * 8;
        int r = e >> 6, c = e & 63;
        const float* src = x + (size_t)(m0 + r) * ND + kc * 64 + c;
        f32x4 f0 = *(const f32x4*)src;
        f32x4 f1 = *(const f32x4*)(src + 4);
        u16x8 u;
        u[0]=f2b(f0[0]); u[1]=f2b(f0[1]); u[2]=f2b(f0[2]); u[3]=f2b(f0[3]);
        u[4]=f2b(f1[0]); u[5]=f2b(f1[1]); u[6]=f2b(f1[2]); u[7]=f2b(f1[3]);
        *(u16x8*)&Alds[r * 64 + (c ^ ((r & 7) << 3))] = u;
      }
    }
#pragma unroll
    for (int p = 0; p < 4; ++p){
      int s = w * 4 + p;
      g2l16(wih_b + (size_t)(n0 + s * 8 + lrow) * ND + kc * 64 + lcol, &Blds[s * 512]);
    }
    __syncthreads();
#pragma unroll
    for (int ks = 0; ks < 2; ++ks){
      int co = ks * 32 + (lane >> 4) * 8;
      int cx = co ^ ((lane & 7) << 3);
      bf16x8 a[4], bb[4];
#pragma unroll
      for (int mi = 0; mi < 4; ++mi)
        a[mi] = *(const bf16x8*)&Alds[(mh + mi * 16 + (lane & 15)) * 64 + cx];
#pragma unroll
      for (int ni = 0; ni < 4; ++ni)
        bb[ni] = *(const bf16x8*)&Blds[(nh + ni * 16 + (lane & 15)) * 64 + cx];
#pragma unroll
      for (int mi = 0; mi < 4; ++mi)
#pragma unroll
        for (int ni = 0; ni < 4; ++ni)
          acc[mi][ni] = __builtin_amdgcn_mfma_f32_16x16x32_bf16(a[mi], bb[ni], acc[mi][ni], 0, 0, 0);
    }
  }

  // ---- epilogue: retire last MFMA reads, then reuse Alds/Blds as transpose scratch ----
  __syncthreads();
  unsigned short* E = (w & 2) ? &Blds[(w & 1) * 4096] : &Alds[(w & 1) * 4096];
#pragma unroll
  for (int mi = 0; mi < 4; ++mi){
#pragma unroll
    for (int rr = 0; rr < 4; ++rr){
      int row_l = mi * 16 + (lane >> 4) * 4 + rr;
#pragma unroll
      for (int ni = 0; ni < 4; ++ni){
        int col_l = ni * 16 + (lane & 15);
        E[row_l * 64 + (col_l ^ ((row_l & 7) << 3))] =
            f2b(acc[mi][ni][rr] + b_ih[n0 + nh + col_l]);
      }
    }
  }
  int r8 = lane >> 3, j8 = lane & 7;
#pragma unroll
  for (int sg = 0; sg < 8; ++sg){
    int row_l = sg * 8 + r8;
    unsigned int prow = perm[m0 + mh + row_l];
    if (prow != 0xFFFFFFFFu){
      u16x8 v = *(const u16x8*)&E[row_l * 64 + ((j8 * 8) ^ ((row_l & 7) << 3))];
      *(u16x8*)(gs + (size_t)prow * G3 + n0 + nh + j8 * 8) = v;
    }
  }
}

// ---------------- step 0: h=0 => gh=b_hh; elementwise over Gsort region 0 ----------------
__global__ __launch_bounds__(256) void k_step0(const float* __restrict__ b_hh,
    const unsigned short* __restrict__ gs,
    const int* __restrict__ sout, const int* __restrict__ cnt_ge,
    unsigned short* __restrict__ hbuf, float* __restrict__ out){
  int nseg = cnt_ge[1];
  int c2 = cnt_ge[2];
  int total = nseg * 128;
  for (int idx = blockIdx.x * 256 + threadIdx.x; idx < total; idx += gridDim.x * 256){
    int i = idx >> 7;
    int c0 = (idx & 127) * 8;
    bool emit = (i >= c2);   // len == 1
    const unsigned short* g = gs + (size_t)i * G3;
    u16x8 vr = __builtin_nontemporal_load((const u16x8*)(g + c0));
    u16x8 vz = __builtin_nontemporal_load((const u16x8*)(g + NH + c0));
    u16x8 vn = __builtin_nontemporal_load((const u16x8*)(g + 2 * NH + c0));
    float hn[8];
#pragma unroll
    for (int j = 0; j < 8; ++j){
      int c = c0 + j;
      float r = sigm(b2f(vr[j]) + b_hh[c]);
      float z = sigm(b2f(vz[j]) + b_hh[NH + c]);
      float n = tanh_(b2f(vn[j]) + r * b_hh[2 * NH + c]);
      hn[j] = (1.0f - z) * n;
    }
    if (emit){
      float* orow = out + (size_t)sout[i] * NH + c0;
      f32x4 v0 = {hn[0], hn[1], hn[2], hn[3]};
      f32x4 v1 = {hn[4], hn[5], hn[6], hn[7]};
      __builtin_nontemporal_store(v0, (f32x4*)orow);
      __builtin_nontemporal_store(v1, (f32x4*)(orow + 4));
    } else {
      u16x8 u;
#pragma unroll
      for (int j = 0; j < 8; ++j) u[j] = f2b(hn[j]);
      *(u16x8*)(hbuf + (size_t)HROWS * NH + (size_t)i * NH + c0) = u;
    }
  }
}

// ---------------- step-tile (k=1..3 big steps): M64 x (3x64), BK=128, 8 phases ----------------
__device__ __forceinline__ void step_tile(int m0, int nc0, int Ak, int c2, int gbase,
    const unsigned short* __restrict__ whh_b, const float* __restrict__ b_hh,
    const unsigned short* __restrict__ gs, const int* __restrict__ sout,
    const unsigned short* __restrict__ hread, unsigned short* __restrict__ hwrite,
    float* __restrict__ out,
    unsigned short (*Alds)[64 * 128], unsigned short (*Blds)[192 * 128]){
  int tid = threadIdx.x;
  int w = tid >> 6, lane = tid & 63;
  int l15 = lane & 15, l4 = lane >> 4;

#define STAGE2(buf, kc) do {                                                        \
    _Pragma("unroll")                                                               \
    for (int p = 0; p < 4; ++p){                                                    \
      int s = w * 4 + p;                                                            \
      int ar = s * 4 + l4;                                                          \
      int sc = (l15 * 8) ^ ((ar & 7) << 3);                                         \
      g2l16(hread + (size_t)(m0 + ar) * NH + (kc) * 128 + sc, &Alds[buf][s * 512]); \
    }                                                                               \
    _Pragma("unroll")                                                               \
    for (int p = 0; p < 12; ++p){                                                   \
      int s = w * 12 + p;                                                           \
      int br = s * 4 + l4;                                                          \
      int wrow = (br >> 6) * NH + nc0 + (br & 63);                                  \
      int sc = (l15 * 8) ^ ((br & 7) << 3);                                         \
      g2l16(whh_b + (size_t)wrow * NH + (kc) * 128 + sc, &Blds[buf][s * 512]);      \
    }                                                                               \
  } while (0)

  STAGE2(0, 0);

  // epilogue-operand prefetch (hidden under the K-loop); gs is stream-once -> nt loads
  int c_lane = nc0 + w * 16 + l15;
  float bh_r = b_hh[c_lane], bh_z = b_hh[NH + c_lane], bh_n = b_hh[2 * NH + c_lane];
  unsigned short gr_[4][4], gz_[4][4], gn_[4][4], hv_[4][4];
  int so_[4][4];
#pragma unroll
  for (int a = 0; a < 4; ++a){
#pragma unroll
    for (int rr = 0; rr < 4; ++rr){
      int i = m0 + a * 16 + l4 * 4 + rr;
      const unsigned short* g = gs + (size_t)(gbase + i) * G3 + c_lane;
      gr_[a][rr] = __builtin_nontemporal_load(g);
      gz_[a][rr] = __builtin_nontemporal_load(g + NH);
      gn_[a][rr] = __builtin_nontemporal_load(g + 2 * NH);
      hv_[a][rr] = hread[(size_t)i * NH + c_lane];
      so_[a][rr] = sout[i < MROWS ? i : 0];
    }
  }

  f32x4 acc[4][3];
#pragma unroll
  for (int a = 0; a < 4; ++a)
#pragma unroll
    for (int b = 0; b < 3; ++b) acc[a][b] = (f32x4){0.f, 0.f, 0.f, 0.f};

  __syncthreads();
  int cur = 0;
  for (int kc = 0; kc < 8; ++kc){
    if (kc < 7) STAGE2(cur ^ 1, kc + 1);
#pragma unroll
    for (int ks = 0; ks < 4; ++ks){
      int co = ks * 32 + l4 * 8;
      bf16x8 av[4], bv[3];
#pragma unroll
      for (int a = 0; a < 4; ++a){
        int r = a * 16 + l15;
        av[a] = *(const bf16x8*)&Alds[cur][r * 128 + (co ^ ((r & 7) << 3))];
      }
#pragma unroll
      for (int b = 0; b < 3; ++b){
        int br = 64 * b + w * 16 + l15;
        bv[b] = *(const bf16x8*)&Blds[cur][br * 128 + (co ^ ((br & 7) << 3))];
      }
#pragma unroll
      for (int a = 0; a < 4; ++a)
#pragma unroll
        for (int b = 0; b < 3; ++b)
          acc[a][b] = __builtin_amdgcn_mfma_f32_16x16x32_bf16(av[a], bv[b], acc[a][b], 0, 0, 0);
    }
    __syncthreads();
    cur ^= 1;
  }
#undef STAGE2

  // fused gate epilogue: one column per lane, 16 rows
#pragma unroll
  for (int a = 0; a < 4; ++a){
#pragma unroll
    for (int rr = 0; rr < 4; ++rr){
      int i = m0 + a * 16 + l4 * 4 + rr;
      if (i >= Ak) continue;
      bool emit = (i >= c2);    // len == k+1
      float ghr = acc[a][0][rr] + bh_r;
      float ghz = acc[a][1][rr] + bh_z;
      float ghn = acc[a][2][rr] + bh_n;
      float h = b2f(hv_[a][rr]);
      float r = sigm(b2f(gr_[a][rr]) + ghr);
      float z = sigm(b2f(gz_[a][rr]) + ghz);
      float n = tanh_(b2f(gn_[a][rr]) + r * ghn);
      float hn = (1.0f - z) * n + z * h;
      if (emit) __builtin_nontemporal_store(hn, &out[(size_t)so_[a][rr] * NH + c_lane]);
      else      hwrite[(size_t)i * NH + c_lane] = f2b(hn);
    }
  }
}

// ---------------- per-step regular kernel (k = 1..3) ----------------
__global__ __launch_bounds__(256, 1) void k_step(int k,
    const unsigned short* __restrict__ whh_b, const float* __restrict__ b_hh,
    const unsigned short* __restrict__ gs, const int* __restrict__ base_g,
    const int* __restrict__ sout, const int* __restrict__ cnt_ge,
    unsigned short* __restrict__ hbuf, float* __restrict__ out){
  __shared__ unsigned short Alds[2][64 * 128];    // 32 KB
  __shared__ unsigned short Blds[2][192 * 128];   // 96 KB
  int Ak = cnt_ge[k + 1];
  if (Ak <= 0) return;
  int c2 = cnt_ge[k + 2];
  int gbase = base_g[k];
  int Mt = (Ak + 63) >> 6;
  int tiles = Mt * 16;
  const unsigned short* hread = hbuf + (size_t)(k & 1) * HROWS * NH;
  unsigned short* hwrite      = hbuf + (size_t)((k + 1) & 1) * HROWS * NH;
  for (int t = blockIdx.x; t < tiles; t += gridDim.x){
    int cs = t & 15, mt = t >> 4;   // gridDim%16==0 -> cs stationary per block
    step_tile(mt * 64, cs * 64, Ak, c2, gbase, whh_b, b_hh, gs, sout,
              hread, hwrite, out, Alds, Blds);
  }
}

// ---------------- persistent tail (k >= 4): W in LDS, 4 blocks/col-slice ----------------
// R17-validated geometry (TAILG=256: cs=bid&63, rg=bid>>6); k=4+ only (R19 showed k=3
// belongs in the LDS-staged k_step regime).
__global__ __launch_bounds__(256, 1) void k_tail(
    const unsigned short* __restrict__ whh_b, const float* __restrict__ b_hh,
    const unsigned short* __restrict__ gs, const int* __restrict__ base_g,
    const int* __restrict__ sout, const int* __restrict__ cnt_ge,
    unsigned short* __restrict__ hbuf, float* __restrict__ out,
    unsigned int* __restrict__ bar){
  __shared__ unsigned short Wlds[48 * 1024];    // 96 KB
  int tid = threadIdx.x;
  int w = tid >> 6, lane = tid & 63;
  int l15 = lane & 15, l4 = lane >> 4;
  int cs = blockIdx.x & 63;                     // col-slice
  int rg = blockIdx.x >> 6;                     // row-group 0..3

  // one-time W preload: LDS[j][c'] = W[grow(j)][c' ^ ((j&7)<<3)], j = gate*16 + col
#pragma unroll
  for (int p = 0; p < 24; ++p){
    int s = w * 24 + p;                         // 0..95
    int r = s >> 1, h = s & 1;
    int grow = (r >> 4) * NH + cs * 16 + (r & 15);
    int cp = h * 512 + lane * 8;
    g2l16(whh_b + (size_t)grow * NH + (cp ^ ((r & 7) << 3)),
          &Wlds[r * 1024 + h * 512 + lane * 8]);
  }
  __syncthreads();                              // drains vmcnt: W resident

  int c_lane = cs * 16 + l15;
  float bh_r = b_hh[c_lane], bh_z = b_hh[NH + c_lane], bh_n = b_hh[2 * NH + c_lane];

  unsigned int phase = 0;
  for (int k = 4; k <= 1023; ++k){
    int Ak = cnt_ge[k + 1];                     // uniform across blocks (read-only)
    if (Ak <= 0) break;
    int c2 = cnt_ge[k + 2];
    int gbase = base_g[k];
    int Mt16 = (Ak + 15) >> 4;
    const unsigned short* hread = hbuf + (size_t)(k & 1) * HROWS * NH;
    unsigned short* hwrite      = hbuf + (size_t)((k + 1) & 1) * HROWS * NH;

    for (int mt = rg * 4 + w; mt < Mt16; mt += 16){
      int m0 = mt * 16;
      unsigned short gr_[4], gz_[4], gn_[4], hv_[4];
      int so_[4];
#pragma unroll
      for (int rr = 0; rr < 4; ++rr){
        int i = m0 + l4 * 4 + rr;
        const unsigned short* g = gs + (size_t)(gbase + i) * G3 + c_lane;
        gr_[rr] = __builtin_nontemporal_load(g);
        gz_[rr] = __builtin_nontemporal_load(g + NH);
        gn_[rr] = __builtin_nontemporal_load(g + 2 * NH);
        hv_[rr] = ld_agent_u16(hread + (size_t)i * NH + c_lane);
        so_[rr] = sout[i < MROWS ? i : 0];
      }

      const unsigned short* arow = hread + (size_t)(m0 + l15) * NH + l4 * 8;
      f32x4 acc0 = {0.f, 0.f, 0.f, 0.f}, acc1 = acc0, acc2 = acc0;
#pragma unroll 8
      for (int ks = 0; ks < 32; ++ks){
        int co = ks * 32 + l4 * 8;
        union { bf16x8 v; unsigned long long q[2]; } a;
        a.q[0] = ld_agent_u64(arow + ks * 32);
        a.q[1] = ld_agent_u64(arow + ks * 32 + 4);
        int cx = co ^ ((l15 & 7) << 3);
        bf16x8 b0 = *(const bf16x8*)&Wlds[(0 * 16 + l15) * 1024 + cx];
        bf16x8 b1 = *(const bf16x8*)&Wlds[(1 * 16 + l15) * 1024 + cx];
        bf16x8 b2 = *(const bf16x8*)&Wlds[(2 * 16 + l15) * 1024 + cx];
        acc0 = __builtin_amdgcn_mfma_f32_16x16x32_bf16(a.v, b0, acc0, 0, 0, 0);
        acc1 = __builtin_amdgcn_mfma_f32_16x16x32_bf16(a.v, b1, acc1, 0, 0, 0);
        acc2 = __builtin_amdgcn_mfma_f32_16x16x32_bf16(a.v, b2, acc2, 0, 0, 0);
      }

#pragma unroll
      for (int rr = 0; rr < 4; ++rr){
        int i = m0 + l4 * 4 + rr;
        if (i >= Ak) continue;
        bool emit = (i >= c2);                  // len == k+1
        float h = b2f(hv_[rr]);
        float r = sigm(b2f(gr_[rr]) + acc0[rr] + bh_r);
        float z = sigm(b2f(gz_[rr]) + acc1[rr] + bh_z);
        float n = tanh_(b2f(gn_[rr]) + r * (acc2[rr] + bh_n));
        float hn = (1.0f - z) * n + z * h;
        if (emit) __builtin_nontemporal_store(hn, &out[(size_t)so_[rr] * NH + c_lane]);
        else      st_agent_u16(hwrite + (size_t)i * NH + c_lane, f2b(hn));
      }
    }

    // fence-free device barrier (validated R11)
    ++phase;
    __syncthreads();
    if (threadIdx.x == 0){
      atomicAdd(bar, 1u);
      unsigned int goal = phase * (unsigned int)TAILG;
      while (__hip_atomic_load(bar, __ATOMIC_RELAXED, __HIP_MEMORY_SCOPE_AGENT) < goal)
        __builtin_amdgcn_s_sleep(2);
    }
    __syncthreads();
  }
}

extern "C" void kernel_launch(void* const* d_in, const int* in_sizes, int n_in,
                              void* d_out, int out_size, void* d_ws, size_t ws_size,
                              hipStream_t stream){
  (void)in_sizes; (void)n_in; (void)out_size;
  const float* x   = (const float*)d_in[0];
  const float* wih = (const float*)d_in[1];
  const float* whh = (const float*)d_in[2];
  const float* bih = (const float*)d_in[3];
  const float* bhh = (const float*)d_in[4];
  const int*   seg = (const int*)d_in[5];
  float* outp = (float*)d_out;

  char* ws = (char*)d_ws;
  size_t o_wih = 0;                                        // 6 MB
  size_t o_whh = 6291456;                                  // 6 MB
  size_t o_gs  = 12582912;                                 // Gsort bf16 ~193 MB
  size_t o_desc = o_gs + (size_t)GSROWS * G3 * 2;          // 2 MB
  size_t o_h    = o_desc + (2u << 20);                     // hbuf: 64.5 MB
  size_t o_xb   = o_h + (size_t)2 * HROWS * NH * 2;        // x_b: 64 MB
  size_t need_xb = o_xb + (size_t)MROWS * ND * 2;
  int has_xb = (ws_size >= need_xb) ? 1 : 0;

  unsigned short* wih_b = (unsigned short*)(ws + o_wih);
  unsigned short* whh_b = (unsigned short*)(ws + o_whh);
  unsigned short* gsort = (unsigned short*)(ws + o_gs);
  int* ugi  = (int*)(ws + o_desc);
  int* uout = ugi + 32768;
  int* ulen = uout + 32768;
  int* sgi  = ulen + 32768;
  int* sout = sgi + 32768;
  int* slen = sout + 32768;
  int* nsegb = slen + 32768;
  int* cntge = nsegb + 64;
  int* baseg = cntge + 1056;
  unsigned int* perm = (unsigned int*)(baseg + 1056);
  unsigned int* bar  = perm + MROWS;
  unsigned short* hbuf = (unsigned short*)(ws + o_h);
  unsigned short* x_b  = (unsigned short*)(ws + o_xb);

  float* counts_out = outp + (size_t)NB * NT * NH;
  int out_n4 = (NB * NT * NH) / 4;   // out proper only; counts written by segbuild block

  k_setup<<<dim3(513), dim3(1024), 0, stream>>>(wih, whh, x, wih_b, whh_b, x_b, has_xb,
                                                (f32x4*)d_out, out_n4,
                                                seg, ugi, uout, ulen, nsegb,
                                                sgi, sout, slen, cntge, baseg,
                                                perm, bar, counts_out);

  k_gi_gemm<<<dim3(256 * 24), dim3(256), 0, stream>>>(x, x_b, wih_b, bih, perm, gsort, has_xb);

  k_step0<<<dim3(1024), dim3(256), 0, stream>>>(bhh, gsort, sout, cntge, hbuf, outp);

  for (int k = 1; k <= 3; ++k){
    k_step<<<dim3(256), dim3(256), 0, stream>>>(k, whh_b, bhh, gsort, baseg,
                                                sout, cntge, hbuf, outp);
  }

  k_tail<<<dim3(TAILG), dim3(256), 0, stream>>>(whh_b, bhh, gsort, baseg,
                                                sout, cntge, hbuf, outp, bar);
}